// Round 8
// baseline (279.128 us; speedup 1.0000x reference)
//
#include <hip/hip_runtime.h>
#include <hip/hip_bf16.h>
#include <stdint.h>

#define T_LEN  2048
#define E_DIM  1024
#define BATCH  4
#define HEADS  16
#define HDIM   64
#define CHUNK_ 128
#define NCHUNK 16
#define EPS_   1e-6f

typedef __attribute__((ext_vector_type(8))) short bf16x8;
typedef __attribute__((ext_vector_type(4))) float f32x4;

__device__ __forceinline__ float b2f(__hip_bfloat16 h) { return __bfloat162float(h); }
__device__ __forceinline__ unsigned short f2bu(float f) {
  __hip_bfloat16 h = __float2bfloat16(f);
  return *(unsigned short*)&h;
}
__device__ __forceinline__ float bs2f(unsigned short v) {
  union { unsigned int u; float f; } c;
  c.u = ((unsigned int)v) << 16;
  return c.f;
}
// async global->LDS, 16B per lane; LDS dest = base + lane*16 (wave-uniform base)
__device__ __forceinline__ void gld_lds16(const void* g, void* l) {
  __builtin_amdgcn_global_load_lds((const __attribute__((address_space(1))) void*)g,
                                   (__attribute__((address_space(3))) void*)l,
                                   16, 0, 0);
}

// ---------------------------------------------------------------------------
// fp32 -> bf16 cast for x (8192x1024) and four 1024x1024 weights.
// ---------------------------------------------------------------------------
__global__ __launch_bounds__(256)
void cast5(const float* __restrict__ x,  const float* __restrict__ w0,
           const float* __restrict__ w1, const float* __restrict__ w2,
           const float* __restrict__ w3,
           __hip_bfloat16* __restrict__ xb,  __hip_bfloat16* __restrict__ w0b,
           __hip_bfloat16* __restrict__ w1b, __hip_bfloat16* __restrict__ w2b,
           __hip_bfloat16* __restrict__ w3b)
{
  const int b = blockIdx.x;
  const float* s;
  __hip_bfloat16* d;
  size_t off;
  if (b < 8192) { s = x; d = xb; off = (size_t)b * 1024; }
  else {
    const int i = (b - 8192) >> 10;
    const int r = (b - 8192) & 1023;
    s = (i == 0) ? w0 : (i == 1) ? w1 : (i == 2) ? w2 : w3;
    d = (i == 0) ? w0b : (i == 1) ? w1b : (i == 2) ? w2b : w3b;
    off = (size_t)r * 1024;
  }
  const int t = threadIdx.x;
  float4 v = *(const float4*)(s + off + (size_t)t * 4);
  ushort4 o;
  o.x = f2bu(v.x); o.y = f2bu(v.y); o.z = f2bu(v.z); o.w = f2bu(v.w);
  *(ushort4*)((unsigned short*)d + off + (size_t)t * 4) = o;
}

// ---------------------------------------------------------------------------
// 128x128 GEMM core (m97 structure): BK=32, global_load_lds width=16,
// LDS row-major [m][32k] (64B rows), wave w owns 64x64 quadrant.
// ---------------------------------------------------------------------------
__device__ __forceinline__ void gemm128_core(
    const __hip_bfloat16* __restrict__ X,
    const __hip_bfloat16* __restrict__ W,
    int bm, int bn, f32x4 acc[4][4],
    __hip_bfloat16* Xs, __hip_bfloat16* Ws)
{
  const int t = threadIdx.x, lane = t & 63, wave = t >> 6;
  const int wm = (wave >> 1) * 64, wn = (wave & 1) * 64;
  for (int k0 = 0; k0 < 1024; k0 += 32) {
    if (k0) __syncthreads();
#pragma unroll
    for (int i = 0; i < 2; ++i) {
      const int j = wave * 2 + i;
      const int m = j * 16 + (lane >> 2);
      const int kg = lane & 3;
      gld_lds16(X + (size_t)(bm * 128 + m) * 1024 + k0 + kg * 8, (char*)Xs + j * 1024);
      gld_lds16(W + (size_t)(bn * 128 + m) * 1024 + k0 + kg * 8, (char*)Ws + j * 1024);
    }
    __syncthreads();
    bf16x8 a[4], b[4];
#pragma unroll
    for (int i = 0; i < 4; ++i) {
      a[i] = *(const bf16x8*)&Xs[((wm + i * 16 + (lane & 15)) * 4 + (lane >> 4)) * 8];
      b[i] = *(const bf16x8*)&Ws[((wn + i * 16 + (lane & 15)) * 4 + (lane >> 4)) * 8];
    }
#pragma unroll
    for (int i = 0; i < 4; ++i)
#pragma unroll
      for (int jn = 0; jn < 4; ++jn)
        acc[i][jn] = __builtin_amdgcn_mfma_f32_16x16x32_bf16(a[i], b[jn], acc[i][jn], 0, 0, 0);
  }
}

// fused q/k/v projection: grid (64, 24); bn>>3 selects {q,k,v}
__global__ __launch_bounds__(256, 2)
void gemm_qkv(const __hip_bfloat16* __restrict__ X,
              const __hip_bfloat16* __restrict__ Wq,
              const __hip_bfloat16* __restrict__ Wk,
              const __hip_bfloat16* __restrict__ Wv,
              __hip_bfloat16* __restrict__ qo,
              __hip_bfloat16* __restrict__ ko,
              __hip_bfloat16* __restrict__ vo)
{
  __shared__ __align__(16) __hip_bfloat16 Xs[128 * 32];
  __shared__ __align__(16) __hip_bfloat16 Ws[128 * 32];
  const int bm = blockIdx.x, bnx = blockIdx.y;
  const int which = bnx >> 3, bn = bnx & 7;
  const __hip_bfloat16* W = (which == 0) ? Wq : (which == 1) ? Wk : Wv;
  __hip_bfloat16* C = (which == 0) ? qo : (which == 1) ? ko : vo;
  const bool elu = (which < 2);
  f32x4 acc[4][4];
#pragma unroll
  for (int i = 0; i < 4; ++i)
#pragma unroll
    for (int j = 0; j < 4; ++j) acc[i][j] = (f32x4){0.f, 0.f, 0.f, 0.f};
  gemm128_core(X, W, bm, bn, acc, Xs, Ws);
  const int lane = threadIdx.x & 63, wave = threadIdx.x >> 6;
  const int wm = (wave >> 1) * 64, wn = (wave & 1) * 64;
  const int r0 = (lane >> 4) * 4;
#pragma unroll
  for (int mi = 0; mi < 4; ++mi)
#pragma unroll
    for (int ni = 0; ni < 4; ++ni) {
      const int row = bm * 128 + wm + mi * 16 + r0;
      const int col = bn * 128 + wn + ni * 16 + (lane & 15);
#pragma unroll
      for (int r = 0; r < 4; ++r) {
        float v = acc[mi][ni][r];
        if (elu) v = (v > 0.f) ? (v + 1.f) : __expf(v);
        C[(size_t)(row + r) * 1024 + col] = __float2bfloat16(v);
      }
    }
}

// output projection: fp32 out + bias; grid (64, 8)
__global__ __launch_bounds__(256, 2)
void gemm_out(const __hip_bfloat16* __restrict__ X,
              const __hip_bfloat16* __restrict__ W,
              const float* __restrict__ bias,
              float* __restrict__ C)
{
  __shared__ __align__(16) __hip_bfloat16 Xs[128 * 32];
  __shared__ __align__(16) __hip_bfloat16 Ws[128 * 32];
  const int bm = blockIdx.x, bn = blockIdx.y;
  f32x4 acc[4][4];
#pragma unroll
  for (int i = 0; i < 4; ++i)
#pragma unroll
    for (int j = 0; j < 4; ++j) acc[i][j] = (f32x4){0.f, 0.f, 0.f, 0.f};
  gemm128_core(X, W, bm, bn, acc, Xs, Ws);
  const int lane = threadIdx.x & 63, wave = threadIdx.x >> 6;
  const int wm = (wave >> 1) * 64, wn = (wave & 1) * 64;
  const int r0 = (lane >> 4) * 4;
#pragma unroll
  for (int mi = 0; mi < 4; ++mi)
#pragma unroll
    for (int ni = 0; ni < 4; ++ni) {
      const int row = bm * 128 + wm + mi * 16 + r0;
      const int col = bn * 128 + wn + ni * 16 + (lane & 15);
      const float bv = bias[col];
#pragma unroll
      for (int r = 0; r < 4; ++r)
        C[(size_t)(row + r) * 1024 + col] = acc[mi][ni][r] + bv;
    }
}

// ---------------------------------------------------------------------------
// Per-chunk KV state in B-frag IMAGE layout (round-4/7 verified structure;
// ONLY change: inner LDS reads vectorized u16 -> ushort4, 4x fewer DS instrs):
//   Simg flat idx = (d>>3)*512 + e*8 + (d&7)  (fp32, per-chunk, NOT prefixed)
// Also emits V image: vimg[bid][sg*64+e][j] = v[sg*8+j][e] (bf16).
// ---------------------------------------------------------------------------
__global__ __launch_bounds__(256)
void chunk_kv(const __hip_bfloat16* __restrict__ Kp,
              const __hip_bfloat16* __restrict__ Vp,
              float* __restrict__ kvout, float* __restrict__ zkout,
              unsigned short* __restrict__ vimg)
{
  const int bid = blockIdx.x;  // b*256 + h*16 + n
  const int n = bid & 15, h = (bid >> 4) & 15, b = bid >> 8;
  __shared__ __align__(16) __hip_bfloat16 ks[CHUNK_ * HDIM];
  __shared__ __align__(16) __hip_bfloat16 vs[CHUNK_ * HDIM];
  const size_t base = ((size_t)(b * T_LEN + n * CHUNK_)) * E_DIM + h * HDIM;
  const int t = threadIdx.x;
  for (int i = t; i < CHUNK_ * 8; i += 256) {
    int r = i >> 3, c = (i & 7) << 3;
    *(uint4*)&ks[r * HDIM + c] = *(const uint4*)(Kp + base + (size_t)r * E_DIM + c);
    *(uint4*)&vs[r * HDIM + c] = *(const uint4*)(Vp + base + (size_t)r * E_DIM + c);
  }
  __syncthreads();
  const int d0 = (t >> 4) << 2, e0 = (t & 15) << 2;
  const unsigned short* ksu = (const unsigned short*)ks;
  const unsigned short* vsu = (const unsigned short*)vs;
  float acc[4][4] = {{0.f}};
  float z[4] = {0.f, 0.f, 0.f, 0.f};
#pragma unroll 4
  for (int c = 0; c < CHUNK_; ++c) {
    const ushort4 ku = *(const ushort4*)&ksu[c * HDIM + d0];   // ds_read_b64
    const ushort4 vu = *(const ushort4*)&vsu[c * HDIM + e0];   // ds_read_b64
    const float kv4[4] = { bs2f(ku.x), bs2f(ku.y), bs2f(ku.z), bs2f(ku.w) };
    const float vv4[4] = { bs2f(vu.x), bs2f(vu.y), bs2f(vu.z), bs2f(vu.w) };
#pragma unroll
    for (int i = 0; i < 4; ++i) {
      z[i] += kv4[i];
#pragma unroll
      for (int j = 0; j < 4; ++j) acc[i][j] += kv4[i] * vv4[j];
    }
  }
  float* o = kvout + (size_t)bid * (HDIM * HDIM);
  const int dg = d0 >> 3, doff = d0 & 7;
#pragma unroll
  for (int i = 0; i < 4; ++i)
#pragma unroll
    for (int j = 0; j < 4; ++j)
      o[dg * 512 + (e0 + j) * 8 + doff + i] = acc[i][j];  // image layout
  if (e0 == 0) {
#pragma unroll
    for (int i = 0; i < 4; ++i) zkout[(size_t)bid * HDIM + d0 + i] = z[i];
  }
  // V image: slot = sg*64+e, elems j -> v[sg*8+j][e]
  unsigned short* vo = vimg + (size_t)bid * 8192;
  for (int slot = t; slot < 1024; slot += 256) {
    const int sg = slot >> 6, e = slot & 63;
    ushort4 lo, hi;
    lo.x = vsu[(sg * 8 + 0) * 64 + e]; lo.y = vsu[(sg * 8 + 1) * 64 + e];
    lo.z = vsu[(sg * 8 + 2) * 64 + e]; lo.w = vsu[(sg * 8 + 3) * 64 + e];
    hi.x = vsu[(sg * 8 + 4) * 64 + e]; hi.y = vsu[(sg * 8 + 5) * 64 + e];
    hi.z = vsu[(sg * 8 + 6) * 64 + e]; hi.w = vsu[(sg * 8 + 7) * 64 + e];
    *(ushort4*)&vo[slot * 8] = lo;
    *(ushort4*)&vo[slot * 8 + 4] = hi;
  }
}

// ---------------------------------------------------------------------------
// Barrier-free MFMA chunk_attn. S_prev/Z_prev are now summed IN-KERNEL from
// the per-chunk tiles (m < n, ascending — bit-identical fp32 order to the old
// prefix kernel). prefix_chunks is deleted.
// ---------------------------------------------------------------------------
#define PW_STRIDE 136  // 272 B row stride: 2-way-free banks, 16B aligned

__global__ __launch_bounds__(256, 3)
void chunk_attn(const __hip_bfloat16* __restrict__ Qp,
                const __hip_bfloat16* __restrict__ Kp,
                const unsigned short* __restrict__ vimg,  // [bid][1024 slots][8]
                const float* __restrict__ Simg,           // [bid][4096] image fp32 (per-chunk)
                const float* __restrict__ Zp,             // [bid][64] (per-chunk)
                __hip_bfloat16* __restrict__ Yp)
{
  __shared__ __align__(16) unsigned short VL[8192];             // 16 KB
  __shared__ __align__(16) unsigned short SL[4096];             // 8 KB
  __shared__ __align__(16) unsigned short PL[4 * 16 * PW_STRIDE];  // 17 KB

  const int bid = blockIdx.x;
  const int n = bid & 15, h = (bid >> 4) & 15, b = bid >> 8;
  const int tokbase = b * T_LEN + n * CHUNK_;
  const size_t gbase = (size_t)tokbase * E_DIM + h * HDIM;
  const int t = threadIdx.x, lane = t & 63, wv = t >> 6;
  const int lm = lane & 15, kg = lane >> 4;

  // ---- stage V image (contiguous async) ----
#pragma unroll
  for (int i = 0; i < 4; ++i) {
    const int j = wv * 4 + i;
    gld_lds16(vimg + (size_t)bid * 8192 + (size_t)(j * 64 + lane) * 8,
              (char*)VL + j * 1024);
  }
  // ---- build S_prev = sum_{m<n} Simg tiles (fp32, ascending) -> bf16 SL ----
  {
    const float* Sg0 = Simg + (size_t)(bid - n) * 4096;
#pragma unroll
    for (int i = 0; i < 4; ++i) {
      const int idx = i * 1024 + t * 4;
      float ax = 0.f, ay = 0.f, az = 0.f, aw = 0.f;
      for (int m = 0; m < n; ++m) {
        const float4 s4 = *(const float4*)(Sg0 + (size_t)m * 4096 + idx);
        ax += s4.x; ay += s4.y; az += s4.z; aw += s4.w;
      }
      ushort4 o;
      o.x = f2bu(ax); o.y = f2bu(ay); o.z = f2bu(az); o.w = f2bu(aw);
      *(ushort4*)&SL[idx] = o;
    }
  }

  const int mts[2] = { wv, 7 - wv };
  // ---- phiq A/B frags from global (layout identical for A and B) ----
  bf16x8 aq[2][2];
#pragma unroll
  for (int mi = 0; mi < 2; ++mi)
#pragma unroll
    for (int kh = 0; kh < 2; ++kh)
      aq[mi][kh] = *(const bf16x8*)(Qp + gbase +
                    (size_t)(mts[mi] * 16 + lm) * E_DIM + kh * 32 + kg * 8);
  // ---- Z_prev broadcast-B frags: sum_{m<n} Zp tiles (ascending) ----
  bf16x8 zb[2];
#pragma unroll
  for (int kh = 0; kh < 2; ++kh) {
    float z8[8];
#pragma unroll
    for (int j = 0; j < 8; ++j) z8[j] = 0.f;
    const float* Zg0 = Zp + (size_t)(bid - n) * 64 + kh * 32 + kg * 8;
    for (int m = 0; m < n; ++m) {
      const float4 a0 = *(const float4*)(Zg0 + (size_t)m * 64);
      const float4 a1 = *(const float4*)(Zg0 + (size_t)m * 64 + 4);
      z8[0] += a0.x; z8[1] += a0.y; z8[2] += a0.z; z8[3] += a0.w;
      z8[4] += a1.x; z8[5] += a1.y; z8[6] += a1.z; z8[7] += a1.w;
    }
#pragma unroll
    for (int j = 0; j < 8; ++j) zb[kh][j] = (short)f2bu(z8[j]);
  }

  __syncthreads();  // the ONLY barrier: all staging (incl. async V) visible

  f32x4 accn[2][4];
  f32x4 accden[2];
#pragma unroll
  for (int mi = 0; mi < 2; ++mi) {
    accden[mi] = (f32x4){EPS_, EPS_, EPS_, EPS_};
#pragma unroll
    for (int ne = 0; ne < 4; ++ne) accn[mi][ne] = (f32x4){0.f, 0.f, 0.f, 0.f};
  }

  // ---- history: num += phiq @ S_prev ; den += phiq . Z ----
#pragma unroll
  for (int mi = 0; mi < 2; ++mi)
#pragma unroll
    for (int kh = 0; kh < 2; ++kh) {
      const bf16x8 a = aq[mi][kh];
      accden[mi] = __builtin_amdgcn_mfma_f32_16x16x32_bf16(a, zb[kh], accden[mi], 0, 0, 0);
#pragma unroll
      for (int ne = 0; ne < 4; ++ne) {
        bf16x8 bs = *(const bf16x8*)&SL[((kh * 4 + kg) * 64 + ne * 16 + lm) * 8];
        accn[mi][ne] = __builtin_amdgcn_mfma_f32_16x16x32_bf16(a, bs, accn[mi][ne], 0, 0, 0);
      }
    }

  // ---- per-wave causal part: PT tiles -> private P LDS -> PV ----
  unsigned short* Pw = PL + wv * 16 * PW_STRIDE;
  bf16x8 ones;
#pragma unroll
  for (int j = 0; j < 8; ++j) ones[j] = (short)0x3F80;

#pragma unroll
  for (int mi = 0; mi < 2; ++mi) {
    const int mt = mts[mi], m0 = mt * 16;
    // PT tiles (s-tile nt, m-cols of tile mt); same wave writes P[m][s]
    for (int nt = 0; nt <= mt; ++nt) {
      f32x4 pt = (f32x4){0.f, 0.f, 0.f, 0.f};
#pragma unroll
      for (int kh = 0; kh < 2; ++kh) {
        bf16x8 ak = *(const bf16x8*)(Kp + gbase +
                     (size_t)(nt * 16 + lm) * E_DIM + kh * 32 + kg * 8);
        pt = __builtin_amdgcn_mfma_f32_16x16x32_bf16(ak, aq[mi][kh], pt, 0, 0, 0);
      }
      unsigned short u[4];
#pragma unroll
      for (int r = 0; r < 4; ++r) {
        float v = pt[r];
        if (nt == mt) {  // diagonal: rows s_local=kg*4+r, cols m_local=lm; keep s<=m
          v = ((kg * 4 + r) <= lm) ? v : 0.f;
        }
        u[r] = f2bu(v);
      }
      const int sidx = lm * PW_STRIDE + nt * 16 + kg * 4;
      *(unsigned*)&Pw[sidx]     = (unsigned)u[0] | ((unsigned)u[1] << 16);
      *(unsigned*)&Pw[sidx + 2] = (unsigned)u[2] | ((unsigned)u[3] << 16);
    }
    // zero-fill to 32-boundary for even mt
    if ((mt & 1) == 0 && lane < 32) {
      const int m = lane >> 1, half = lane & 1;
      *(uint4*)&Pw[m * PW_STRIDE + (mt + 1) * 16 + half * 8] = (uint4){0u, 0u, 0u, 0u};
    }
    // PV + rowsum(P)
    const int ktc = (mt + 2) >> 1;
    for (int kt = 0; kt < ktc; ++kt) {
      bf16x8 ap = *(const bf16x8*)&Pw[lm * PW_STRIDE + kt * 32 + kg * 8];
      accden[mi] = __builtin_amdgcn_mfma_f32_16x16x32_bf16(ap, ones, accden[mi], 0, 0, 0);
#pragma unroll
      for (int ne = 0; ne < 4; ++ne) {
        bf16x8 bv = *(const bf16x8*)&VL[((kt * 4 + kg) * 64 + ne * 16 + lm) * 8];
        accn[mi][ne] = __builtin_amdgcn_mfma_f32_16x16x32_bf16(ap, bv, accn[mi][ne], 0, 0, 0);
      }
    }
  }

  // ---- epilogue: y = num / den (accden rows == accn rows) ----
#pragma unroll
  for (int mi = 0; mi < 2; ++mi) {
    const int m0 = mts[mi] * 16;
    float inv[4];
#pragma unroll
    for (int r = 0; r < 4; ++r) inv[r] = 1.f / accden[mi][r];
#pragma unroll
    for (int ne = 0; ne < 4; ++ne) {
      const int col = h * HDIM + ne * 16 + lm;
#pragma unroll
      for (int r = 0; r < 4; ++r) {
        const int row = tokbase + m0 + kg * 4 + r;
        Yp[(size_t)row * E_DIM + col] = __float2bfloat16(accn[mi][ne][r] * inv[r]);
      }
    }
  }
}

// ---------------------------------------------------------------------------
extern "C" void kernel_launch(void* const* d_in, const int* in_sizes, int n_in,
                              void* d_out, int out_size, void* d_ws, size_t ws_size,
                              hipStream_t stream)
{
  const float* x  = (const float*)d_in[0];
  const float* Wq = (const float*)d_in[1];
  const float* Wk = (const float*)d_in[2];
  const float* Wv = (const float*)d_in[3];
  const float* Wp = (const float*)d_in[4];
  const float* bp = (const float*)d_in[5];
  float* out = (float*)d_out;

  const size_t MT = (size_t)BATCH * T_LEN;  // 8192 rows
  char* w = (char*)d_ws;
  __hip_bfloat16* xb  = (__hip_bfloat16*)w; w += MT * E_DIM * sizeof(__hip_bfloat16);
  __hip_bfloat16* Wqb = (__hip_bfloat16*)w; w += (size_t)E_DIM * E_DIM * sizeof(__hip_bfloat16);
  __hip_bfloat16* Wkb = (__hip_bfloat16*)w; w += (size_t)E_DIM * E_DIM * sizeof(__hip_bfloat16);
  __hip_bfloat16* Wvb = (__hip_bfloat16*)w; w += (size_t)E_DIM * E_DIM * sizeof(__hip_bfloat16);
  __hip_bfloat16* Wpb = (__hip_bfloat16*)w; w += (size_t)E_DIM * E_DIM * sizeof(__hip_bfloat16);
  __hip_bfloat16* q = (__hip_bfloat16*)w; w += MT * E_DIM * sizeof(__hip_bfloat16);
  __hip_bfloat16* k = (__hip_bfloat16*)w; w += MT * E_DIM * sizeof(__hip_bfloat16);
  __hip_bfloat16* v = (__hip_bfloat16*)w; w += MT * E_DIM * sizeof(__hip_bfloat16);
  __hip_bfloat16* y = (__hip_bfloat16*)w; w += MT * E_DIM * sizeof(__hip_bfloat16);
  float* S = (float*)w; w += (size_t)BATCH * HEADS * NCHUNK * HDIM * HDIM * sizeof(float);
  float* Z = (float*)w; w += (size_t)BATCH * HEADS * NCHUNK * HDIM * sizeof(float);
  // V image reuses xb (dead after gemm_qkv; chunk_kv runs strictly after)
  unsigned short* vimg = (unsigned short*)xb;

  cast5<<<8192 + 4096, 256, 0, stream>>>(x, Wq, Wk, Wv, Wp, xb, Wqb, Wkb, Wvb, Wpb);
  gemm_qkv<<<dim3(MT / 128, 24), 256, 0, stream>>>(xb, Wqb, Wkb, Wvb, q, k, v);
  chunk_kv<<<BATCH * HEADS * NCHUNK, 256, 0, stream>>>(k, v, S, Z, vimg);
  chunk_attn<<<BATCH * HEADS * NCHUNK, 256, 0, stream>>>(q, k, vimg, S, Z, y);
  gemm_out<<<dim3(MT / 128, 8), 256, 0, stream>>>(y, Wpb, bp, out);
}

// Round 9
// 248.663 us; speedup vs baseline: 1.1225x; 1.1225x over previous
//
#include <hip/hip_runtime.h>
#include <hip/hip_bf16.h>
#include <stdint.h>

#define T_LEN  2048
#define E_DIM  1024
#define BATCH  4
#define HEADS  16
#define HDIM   64
#define CHUNK_ 128
#define NCHUNK 16
#define EPS_   1e-6f

typedef __attribute__((ext_vector_type(8))) short bf16x8;
typedef __attribute__((ext_vector_type(4))) float f32x4;

__device__ __forceinline__ float b2f(__hip_bfloat16 h) { return __bfloat162float(h); }
__device__ __forceinline__ unsigned short f2bu(float f) {
  __hip_bfloat16 h = __float2bfloat16(f);
  return *(unsigned short*)&h;
}
__device__ __forceinline__ float bs2f(unsigned short v) {
  union { unsigned int u; float f; } c;
  c.u = ((unsigned int)v) << 16;
  return c.f;
}
// async global->LDS, 16B per lane; LDS dest = base + lane*16 (wave-uniform base)
__device__ __forceinline__ void gld_lds16(const void* g, void* l) {
  __builtin_amdgcn_global_load_lds((const __attribute__((address_space(1))) void*)g,
                                   (__attribute__((address_space(3))) void*)l,
                                   16, 0, 0);
}

// ---------------------------------------------------------------------------
// fp32 -> bf16 cast for x (8192x1024) and four 1024x1024 weights.
// ---------------------------------------------------------------------------
__global__ __launch_bounds__(256)
void cast5(const float* __restrict__ x,  const float* __restrict__ w0,
           const float* __restrict__ w1, const float* __restrict__ w2,
           const float* __restrict__ w3,
           __hip_bfloat16* __restrict__ xb,  __hip_bfloat16* __restrict__ w0b,
           __hip_bfloat16* __restrict__ w1b, __hip_bfloat16* __restrict__ w2b,
           __hip_bfloat16* __restrict__ w3b)
{
  const int b = blockIdx.x;
  const float* s;
  __hip_bfloat16* d;
  size_t off;
  if (b < 8192) { s = x; d = xb; off = (size_t)b * 1024; }
  else {
    const int i = (b - 8192) >> 10;
    const int r = (b - 8192) & 1023;
    s = (i == 0) ? w0 : (i == 1) ? w1 : (i == 2) ? w2 : w3;
    d = (i == 0) ? w0b : (i == 1) ? w1b : (i == 2) ? w2b : w3b;
    off = (size_t)r * 1024;
  }
  const int t = threadIdx.x;
  float4 v = *(const float4*)(s + off + (size_t)t * 4);
  ushort4 o;
  o.x = f2bu(v.x); o.y = f2bu(v.y); o.z = f2bu(v.z); o.w = f2bu(v.w);
  *(ushort4*)((unsigned short*)d + off + (size_t)t * 4) = o;
}

// ---------------------------------------------------------------------------
// 128x128 GEMM core (m97 structure): BK=32, global_load_lds width=16,
// LDS row-major [m][32k] (64B rows), wave w owns 64x64 quadrant.
// ---------------------------------------------------------------------------
__device__ __forceinline__ void gemm128_core(
    const __hip_bfloat16* __restrict__ X,
    const __hip_bfloat16* __restrict__ W,
    int bm, int bn, f32x4 acc[4][4],
    __hip_bfloat16* Xs, __hip_bfloat16* Ws)
{
  const int t = threadIdx.x, lane = t & 63, wave = t >> 6;
  const int wm = (wave >> 1) * 64, wn = (wave & 1) * 64;
  for (int k0 = 0; k0 < 1024; k0 += 32) {
    if (k0) __syncthreads();
#pragma unroll
    for (int i = 0; i < 2; ++i) {
      const int j = wave * 2 + i;
      const int m = j * 16 + (lane >> 2);
      const int kg = lane & 3;
      gld_lds16(X + (size_t)(bm * 128 + m) * 1024 + k0 + kg * 8, (char*)Xs + j * 1024);
      gld_lds16(W + (size_t)(bn * 128 + m) * 1024 + k0 + kg * 8, (char*)Ws + j * 1024);
    }
    __syncthreads();
    bf16x8 a[4], b[4];
#pragma unroll
    for (int i = 0; i < 4; ++i) {
      a[i] = *(const bf16x8*)&Xs[((wm + i * 16 + (lane & 15)) * 4 + (lane >> 4)) * 8];
      b[i] = *(const bf16x8*)&Ws[((wn + i * 16 + (lane & 15)) * 4 + (lane >> 4)) * 8];
    }
#pragma unroll
    for (int i = 0; i < 4; ++i)
#pragma unroll
      for (int jn = 0; jn < 4; ++jn)
        acc[i][jn] = __builtin_amdgcn_mfma_f32_16x16x32_bf16(a[i], b[jn], acc[i][jn], 0, 0, 0);
  }
}

// fused q/k/v projection: grid (64, 24); bn>>3 selects {q,k,v}
__global__ __launch_bounds__(256, 2)
void gemm_qkv(const __hip_bfloat16* __restrict__ X,
              const __hip_bfloat16* __restrict__ Wq,
              const __hip_bfloat16* __restrict__ Wk,
              const __hip_bfloat16* __restrict__ Wv,
              __hip_bfloat16* __restrict__ qo,
              __hip_bfloat16* __restrict__ ko,
              __hip_bfloat16* __restrict__ vo)
{
  __shared__ __align__(16) __hip_bfloat16 Xs[128 * 32];
  __shared__ __align__(16) __hip_bfloat16 Ws[128 * 32];
  const int bm = blockIdx.x, bnx = blockIdx.y;
  const int which = bnx >> 3, bn = bnx & 7;
  const __hip_bfloat16* W = (which == 0) ? Wq : (which == 1) ? Wk : Wv;
  __hip_bfloat16* C = (which == 0) ? qo : (which == 1) ? ko : vo;
  const bool elu = (which < 2);
  f32x4 acc[4][4];
#pragma unroll
  for (int i = 0; i < 4; ++i)
#pragma unroll
    for (int j = 0; j < 4; ++j) acc[i][j] = (f32x4){0.f, 0.f, 0.f, 0.f};
  gemm128_core(X, W, bm, bn, acc, Xs, Ws);
  const int lane = threadIdx.x & 63, wave = threadIdx.x >> 6;
  const int wm = (wave >> 1) * 64, wn = (wave & 1) * 64;
  const int r0 = (lane >> 4) * 4;
#pragma unroll
  for (int mi = 0; mi < 4; ++mi)
#pragma unroll
    for (int ni = 0; ni < 4; ++ni) {
      const int row = bm * 128 + wm + mi * 16 + r0;
      const int col = bn * 128 + wn + ni * 16 + (lane & 15);
#pragma unroll
      for (int r = 0; r < 4; ++r) {
        float v = acc[mi][ni][r];
        if (elu) v = (v > 0.f) ? (v + 1.f) : __expf(v);
        C[(size_t)(row + r) * 1024 + col] = __float2bfloat16(v);
      }
    }
}

// output projection: fp32 out + bias; grid (64, 8)
__global__ __launch_bounds__(256, 2)
void gemm_out(const __hip_bfloat16* __restrict__ X,
              const __hip_bfloat16* __restrict__ W,
              const float* __restrict__ bias,
              float* __restrict__ C)
{
  __shared__ __align__(16) __hip_bfloat16 Xs[128 * 32];
  __shared__ __align__(16) __hip_bfloat16 Ws[128 * 32];
  const int bm = blockIdx.x, bn = blockIdx.y;
  f32x4 acc[4][4];
#pragma unroll
  for (int i = 0; i < 4; ++i)
#pragma unroll
    for (int j = 0; j < 4; ++j) acc[i][j] = (f32x4){0.f, 0.f, 0.f, 0.f};
  gemm128_core(X, W, bm, bn, acc, Xs, Ws);
  const int lane = threadIdx.x & 63, wave = threadIdx.x >> 6;
  const int wm = (wave >> 1) * 64, wn = (wave & 1) * 64;
  const int r0 = (lane >> 4) * 4;
#pragma unroll
  for (int mi = 0; mi < 4; ++mi)
#pragma unroll
    for (int ni = 0; ni < 4; ++ni) {
      const int row = bm * 128 + wm + mi * 16 + r0;
      const int col = bn * 128 + wn + ni * 16 + (lane & 15);
      const float bv = bias[col];
#pragma unroll
      for (int r = 0; r < 4; ++r)
        C[(size_t)(row + r) * 1024 + col] = acc[mi][ni][r] + bv;
    }
}

// ---------------------------------------------------------------------------
// Per-chunk KV state in B-frag IMAGE layout (round-8 verified, vectorized):
//   Simg flat idx = (d>>3)*512 + e*8 + (d&7)  (fp32, prefix-summed later)
// Also emits V image: vimg[bid][sg*64+e][j] = v[sg*8+j][e] (bf16).
// ---------------------------------------------------------------------------
__global__ __launch_bounds__(256)
void chunk_kv(const __hip_bfloat16* __restrict__ Kp,
              const __hip_bfloat16* __restrict__ Vp,
              float* __restrict__ kvout, float* __restrict__ zkout,
              unsigned short* __restrict__ vimg)
{
  const int bid = blockIdx.x;  // b*256 + h*16 + n
  const int n = bid & 15, h = (bid >> 4) & 15, b = bid >> 8;
  __shared__ __align__(16) __hip_bfloat16 ks[CHUNK_ * HDIM];
  __shared__ __align__(16) __hip_bfloat16 vs[CHUNK_ * HDIM];
  const size_t base = ((size_t)(b * T_LEN + n * CHUNK_)) * E_DIM + h * HDIM;
  const int t = threadIdx.x;
  for (int i = t; i < CHUNK_ * 8; i += 256) {
    int r = i >> 3, c = (i & 7) << 3;
    *(uint4*)&ks[r * HDIM + c] = *(const uint4*)(Kp + base + (size_t)r * E_DIM + c);
    *(uint4*)&vs[r * HDIM + c] = *(const uint4*)(Vp + base + (size_t)r * E_DIM + c);
  }
  __syncthreads();
  const int d0 = (t >> 4) << 2, e0 = (t & 15) << 2;
  const unsigned short* ksu = (const unsigned short*)ks;
  const unsigned short* vsu = (const unsigned short*)vs;
  float acc[4][4] = {{0.f}};
  float z[4] = {0.f, 0.f, 0.f, 0.f};
#pragma unroll 4
  for (int c = 0; c < CHUNK_; ++c) {
    const ushort4 ku = *(const ushort4*)&ksu[c * HDIM + d0];   // ds_read_b64
    const ushort4 vu = *(const ushort4*)&vsu[c * HDIM + e0];   // ds_read_b64
    const float kv4[4] = { bs2f(ku.x), bs2f(ku.y), bs2f(ku.z), bs2f(ku.w) };
    const float vv4[4] = { bs2f(vu.x), bs2f(vu.y), bs2f(vu.z), bs2f(vu.w) };
#pragma unroll
    for (int i = 0; i < 4; ++i) {
      z[i] += kv4[i];
#pragma unroll
      for (int j = 0; j < 4; ++j) acc[i][j] += kv4[i] * vv4[j];
    }
  }
  float* o = kvout + (size_t)bid * (HDIM * HDIM);
  const int dg = d0 >> 3, doff = d0 & 7;
#pragma unroll
  for (int i = 0; i < 4; ++i)
#pragma unroll
    for (int j = 0; j < 4; ++j)
      o[dg * 512 + (e0 + j) * 8 + doff + i] = acc[i][j];  // image layout
  if (e0 == 0) {
#pragma unroll
    for (int i = 0; i < 4; ++i) zkout[(size_t)bid * HDIM + d0 + i] = z[i];
  }
  // V image: slot = sg*64+e, elems j -> v[sg*8+j][e]
  unsigned short* vo = vimg + (size_t)bid * 8192;
  for (int slot = t; slot < 1024; slot += 256) {
    const int sg = slot >> 6, e = slot & 63;
    ushort4 lo, hi;
    lo.x = vsu[(sg * 8 + 0) * 64 + e]; lo.y = vsu[(sg * 8 + 1) * 64 + e];
    lo.z = vsu[(sg * 8 + 2) * 64 + e]; lo.w = vsu[(sg * 8 + 3) * 64 + e];
    hi.x = vsu[(sg * 8 + 4) * 64 + e]; hi.y = vsu[(sg * 8 + 5) * 64 + e];
    hi.z = vsu[(sg * 8 + 6) * 64 + e]; hi.w = vsu[(sg * 8 + 7) * 64 + e];
    *(ushort4*)&vo[slot * 8] = lo;
    *(ushort4*)&vo[slot * 8 + 4] = hi;
  }
}

// ---------------------------------------------------------------------------
// In-place exclusive prefix over chunks (elementwise; layout-agnostic).
// RESTORED: O(N) prefix beats O(N^2) in-attn fusion (round-8 regression).
// ---------------------------------------------------------------------------
__global__ __launch_bounds__(256)
void prefix_chunks(float* __restrict__ S, float* __restrict__ Z)
{
  const int bh = blockIdx.x;
  const int t = threadIdx.x;
  float run[16];
#pragma unroll
  for (int j = 0; j < 16; ++j) run[j] = 0.f;
  for (int n = 0; n < NCHUNK; ++n) {
    float* p = S + ((size_t)bh * NCHUNK + n) * (HDIM * HDIM);
#pragma unroll
    for (int j = 0; j < 16; ++j) {
      int idx = t + j * 256;
      float cur = p[idx];
      p[idx] = run[j];
      run[j] += cur;
    }
  }
  if (t < HDIM) {
    float rz = 0.f;
    for (int n = 0; n < NCHUNK; ++n) {
      float* p = Z + ((size_t)bh * NCHUNK + n) * HDIM + t;
      float cur = *p;
      *p = rz;
      rz += cur;
    }
  }
}

// ---------------------------------------------------------------------------
// Barrier-free MFMA chunk_attn (round-4/7 verified; prefixed S/Z inputs).
// ---------------------------------------------------------------------------
#define PW_STRIDE 136  // 272 B row stride: 2-way-free banks, 16B aligned

__global__ __launch_bounds__(256, 3)
void chunk_attn(const __hip_bfloat16* __restrict__ Qp,
                const __hip_bfloat16* __restrict__ Kp,
                const unsigned short* __restrict__ vimg,  // [bid][1024 slots][8]
                const float* __restrict__ Simg,           // [bid][4096] image fp32
                const float* __restrict__ Zp,             // [bid][64]
                __hip_bfloat16* __restrict__ Yp)
{
  __shared__ __align__(16) unsigned short VL[8192];             // 16 KB
  __shared__ __align__(16) unsigned short SL[4096];             // 8 KB
  __shared__ __align__(16) unsigned short PL[4 * 16 * PW_STRIDE];  // 17 KB

  const int bid = blockIdx.x;
  const int n = bid & 15, h = (bid >> 4) & 15, b = bid >> 8;
  const int tokbase = b * T_LEN + n * CHUNK_;
  const size_t gbase = (size_t)tokbase * E_DIM + h * HDIM;
  const int t = threadIdx.x, lane = t & 63, wv = t >> 6;
  const int lm = lane & 15, kg = lane >> 4;

  // ---- stage V image (contiguous async) ----
#pragma unroll
  for (int i = 0; i < 4; ++i) {
    const int j = wv * 4 + i;
    gld_lds16(vimg + (size_t)bid * 8192 + (size_t)(j * 64 + lane) * 8,
              (char*)VL + j * 1024);
  }
  // ---- stage S image fp32 -> bf16 (contiguous) ----
#pragma unroll
  for (int i = 0; i < 4; ++i) {
    const int idx = i * 1024 + t * 4;
    float4 s4 = *(const float4*)(Simg + (size_t)bid * 4096 + idx);
    ushort4 o;
    o.x = f2bu(s4.x); o.y = f2bu(s4.y); o.z = f2bu(s4.z); o.w = f2bu(s4.w);
    *(ushort4*)&SL[idx] = o;
  }

  const int mts[2] = { wv, 7 - wv };
  // ---- phiq A/B frags from global (layout identical for A and B) ----
  bf16x8 aq[2][2];
#pragma unroll
  for (int mi = 0; mi < 2; ++mi)
#pragma unroll
    for (int kh = 0; kh < 2; ++kh)
      aq[mi][kh] = *(const bf16x8*)(Qp + gbase +
                    (size_t)(mts[mi] * 16 + lm) * E_DIM + kh * 32 + kg * 8);
  // ---- Z broadcast-B frags (value depends only on k) ----
  bf16x8 zb[2];
#pragma unroll
  for (int kh = 0; kh < 2; ++kh) {
    float4 z0 = *(const float4*)(Zp + (size_t)bid * 64 + kh * 32 + kg * 8);
    float4 z1 = *(const float4*)(Zp + (size_t)bid * 64 + kh * 32 + kg * 8 + 4);
    zb[kh][0] = (short)f2bu(z0.x); zb[kh][1] = (short)f2bu(z0.y);
    zb[kh][2] = (short)f2bu(z0.z); zb[kh][3] = (short)f2bu(z0.w);
    zb[kh][4] = (short)f2bu(z1.x); zb[kh][5] = (short)f2bu(z1.y);
    zb[kh][6] = (short)f2bu(z1.z); zb[kh][7] = (short)f2bu(z1.w);
  }

  __syncthreads();  // the ONLY barrier: all staging (incl. async V) visible

  f32x4 accn[2][4];
  f32x4 accden[2];
#pragma unroll
  for (int mi = 0; mi < 2; ++mi) {
    accden[mi] = (f32x4){EPS_, EPS_, EPS_, EPS_};
#pragma unroll
    for (int ne = 0; ne < 4; ++ne) accn[mi][ne] = (f32x4){0.f, 0.f, 0.f, 0.f};
  }

  // ---- history: num += phiq @ S_prev ; den += phiq . Z ----
#pragma unroll
  for (int mi = 0; mi < 2; ++mi)
#pragma unroll
    for (int kh = 0; kh < 2; ++kh) {
      const bf16x8 a = aq[mi][kh];
      accden[mi] = __builtin_amdgcn_mfma_f32_16x16x32_bf16(a, zb[kh], accden[mi], 0, 0, 0);
#pragma unroll
      for (int ne = 0; ne < 4; ++ne) {
        bf16x8 bs = *(const bf16x8*)&SL[((kh * 4 + kg) * 64 + ne * 16 + lm) * 8];
        accn[mi][ne] = __builtin_amdgcn_mfma_f32_16x16x32_bf16(a, bs, accn[mi][ne], 0, 0, 0);
      }
    }

  // ---- per-wave causal part: PT tiles -> private P LDS -> PV ----
  unsigned short* Pw = PL + wv * 16 * PW_STRIDE;
  bf16x8 ones;
#pragma unroll
  for (int j = 0; j < 8; ++j) ones[j] = (short)0x3F80;

#pragma unroll
  for (int mi = 0; mi < 2; ++mi) {
    const int mt = mts[mi], m0 = mt * 16;
    // PT tiles (s-tile nt, m-cols of tile mt); same wave writes P[m][s]
    for (int nt = 0; nt <= mt; ++nt) {
      f32x4 pt = (f32x4){0.f, 0.f, 0.f, 0.f};
#pragma unroll
      for (int kh = 0; kh < 2; ++kh) {
        bf16x8 ak = *(const bf16x8*)(Kp + gbase +
                     (size_t)(nt * 16 + lm) * E_DIM + kh * 32 + kg * 8);
        pt = __builtin_amdgcn_mfma_f32_16x16x32_bf16(ak, aq[mi][kh], pt, 0, 0, 0);
      }
      unsigned short u[4];
#pragma unroll
      for (int r = 0; r < 4; ++r) {
        float v = pt[r];
        if (nt == mt) {  // diagonal: rows s_local=kg*4+r, cols m_local=lm; keep s<=m
          v = ((kg * 4 + r) <= lm) ? v : 0.f;
        }
        u[r] = f2bu(v);
      }
      const int sidx = lm * PW_STRIDE + nt * 16 + kg * 4;
      *(unsigned*)&Pw[sidx]     = (unsigned)u[0] | ((unsigned)u[1] << 16);
      *(unsigned*)&Pw[sidx + 2] = (unsigned)u[2] | ((unsigned)u[3] << 16);
    }
    // zero-fill to 32-boundary for even mt
    if ((mt & 1) == 0 && lane < 32) {
      const int m = lane >> 1, half = lane & 1;
      *(uint4*)&Pw[m * PW_STRIDE + (mt + 1) * 16 + half * 8] = (uint4){0u, 0u, 0u, 0u};
    }
    // PV + rowsum(P)
    const int ktc = (mt + 2) >> 1;
    for (int kt = 0; kt < ktc; ++kt) {
      bf16x8 ap = *(const bf16x8*)&Pw[lm * PW_STRIDE + kt * 32 + kg * 8];
      accden[mi] = __builtin_amdgcn_mfma_f32_16x16x32_bf16(ap, ones, accden[mi], 0, 0, 0);
#pragma unroll
      for (int ne = 0; ne < 4; ++ne) {
        bf16x8 bv = *(const bf16x8*)&VL[((kt * 4 + kg) * 64 + ne * 16 + lm) * 8];
        accn[mi][ne] = __builtin_amdgcn_mfma_f32_16x16x32_bf16(ap, bv, accn[mi][ne], 0, 0, 0);
      }
    }
  }

  // ---- epilogue: y = num / den (accden rows == accn rows) ----
#pragma unroll
  for (int mi = 0; mi < 2; ++mi) {
    const int m0 = mts[mi] * 16;
    float inv[4];
#pragma unroll
    for (int r = 0; r < 4; ++r) inv[r] = 1.f / accden[mi][r];
#pragma unroll
    for (int ne = 0; ne < 4; ++ne) {
      const int col = h * HDIM + ne * 16 + lm;
#pragma unroll
      for (int r = 0; r < 4; ++r) {
        const int row = tokbase + m0 + kg * 4 + r;
        Yp[(size_t)row * E_DIM + col] = __float2bfloat16(accn[mi][ne][r] * inv[r]);
      }
    }
  }
}

// ---------------------------------------------------------------------------
extern "C" void kernel_launch(void* const* d_in, const int* in_sizes, int n_in,
                              void* d_out, int out_size, void* d_ws, size_t ws_size,
                              hipStream_t stream)
{
  const float* x  = (const float*)d_in[0];
  const float* Wq = (const float*)d_in[1];
  const float* Wk = (const float*)d_in[2];
  const float* Wv = (const float*)d_in[3];
  const float* Wp = (const float*)d_in[4];
  const float* bp = (const float*)d_in[5];
  float* out = (float*)d_out;

  const size_t MT = (size_t)BATCH * T_LEN;  // 8192 rows
  char* w = (char*)d_ws;
  __hip_bfloat16* xb  = (__hip_bfloat16*)w; w += MT * E_DIM * sizeof(__hip_bfloat16);
  __hip_bfloat16* Wqb = (__hip_bfloat16*)w; w += (size_t)E_DIM * E_DIM * sizeof(__hip_bfloat16);
  __hip_bfloat16* Wkb = (__hip_bfloat16*)w; w += (size_t)E_DIM * E_DIM * sizeof(__hip_bfloat16);
  __hip_bfloat16* Wvb = (__hip_bfloat16*)w; w += (size_t)E_DIM * E_DIM * sizeof(__hip_bfloat16);
  __hip_bfloat16* Wpb = (__hip_bfloat16*)w; w += (size_t)E_DIM * E_DIM * sizeof(__hip_bfloat16);
  __hip_bfloat16* q = (__hip_bfloat16*)w; w += MT * E_DIM * sizeof(__hip_bfloat16);
  __hip_bfloat16* k = (__hip_bfloat16*)w; w += MT * E_DIM * sizeof(__hip_bfloat16);
  __hip_bfloat16* v = (__hip_bfloat16*)w; w += MT * E_DIM * sizeof(__hip_bfloat16);
  __hip_bfloat16* y = (__hip_bfloat16*)w; w += MT * E_DIM * sizeof(__hip_bfloat16);
  float* S = (float*)w; w += (size_t)BATCH * HEADS * NCHUNK * HDIM * HDIM * sizeof(float);
  float* Z = (float*)w; w += (size_t)BATCH * HEADS * NCHUNK * HDIM * sizeof(float);
  // V image reuses xb (dead after gemm_qkv; chunk_kv runs strictly after)
  unsigned short* vimg = (unsigned short*)xb;

  cast5<<<8192 + 4096, 256, 0, stream>>>(x, Wq, Wk, Wv, Wp, xb, Wqb, Wkb, Wvb, Wpb);
  gemm_qkv<<<dim3(MT / 128, 24), 256, 0, stream>>>(xb, Wqb, Wkb, Wvb, q, k, v);
  chunk_kv<<<BATCH * HEADS * NCHUNK, 256, 0, stream>>>(k, v, S, Z, vimg);
  prefix_chunks<<<BATCH * HEADS, 256, 0, stream>>>(S, Z);
  chunk_attn<<<BATCH * HEADS * NCHUNK, 256, 0, stream>>>(q, k, vimg, S, Z, y);
  gemm_out<<<dim3(MT / 128, 8), 256, 0, stream>>>(y, Wpb, bp, out);
}